// Round 1
// baseline (647.666 us; speedup 1.0000x reference)
//
#include <hip/hip_runtime.h>
#include <math.h>

#define NHEADS 64            // B*H
#define SEQ    4096
#define DIM    64
#define ELEMS  (NHEADS * SEQ * DIM)   // 16777216 per tensor

// workspace layout (floats):
//   [0,1024)      partial qsum
//   [1024,2048)   partial qsumsq
//   [2048,3072)   partial ksum
//   [3072,4096)   partial ksumsq
//   [4096,5120)   partial kmax
//   [5120,5248)   params: [0]=alpha [1]=beta [2+h]=beta*kmax[h]
//   [6144,10240)  Ksum  [64 heads][64]
//   [10240,272384) KV   [64 heads][64][64]

__device__ __forceinline__ float wave_reduce_sum(float v) {
#pragma unroll
    for (int m = 32; m > 0; m >>= 1) v += __shfl_xor(v, m);
    return v;
}
__device__ __forceinline__ float wave_reduce_max(float v) {
#pragma unroll
    for (int m = 32; m > 0; m >>= 1) v = fmaxf(v, __shfl_xor(v, m));
    return v;
}

// ---------------- Kernel 1: per-block stats (sum, sumsq, optional max) ---------
__global__ __launch_bounds__(256) void reduce_stats(const float* __restrict__ x,
                                                    float* __restrict__ psum,
                                                    float* __restrict__ psumsq,
                                                    float* __restrict__ pmax) {
    int t = threadIdx.x;
    const float4* x4 = (const float4*)(x + (long)blockIdx.x * 16384);
    float s = 0.f, sq = 0.f, mx = -1e30f;
#pragma unroll
    for (int it = 0; it < 16; ++it) {
        float4 v = x4[it * 256 + t];
        s += v.x + v.y + v.z + v.w;
        sq += v.x * v.x + v.y * v.y + v.z * v.z + v.w * v.w;
        mx = fmaxf(mx, fmaxf(fmaxf(v.x, v.y), fmaxf(v.z, v.w)));
    }
    s = wave_reduce_sum(s);
    sq = wave_reduce_sum(sq);
    mx = wave_reduce_max(mx);
    __shared__ float ls[4], lsq[4], lm[4];
    int w = t >> 6, lane = t & 63;
    if (lane == 0) { ls[w] = s; lsq[w] = sq; lm[w] = mx; }
    __syncthreads();
    if (t == 0) {
        float S = 0.f, SQ = 0.f, M = -1e30f;
        for (int i = 0; i < 4; ++i) { S += ls[i]; SQ += lsq[i]; M = fmaxf(M, lm[i]); }
        psum[blockIdx.x] = S;
        psumsq[blockIdx.x] = SQ;
        if (pmax) pmax[blockIdx.x] = M;
    }
}

// ---------------- Kernel 2: alpha/beta + per-head scaled kmax ------------------
__global__ __launch_bounds__(256) void compute_params(float* __restrict__ ws) {
    const float* pqs = ws;
    const float* pqq = ws + 1024;
    const float* pks = ws + 2048;
    const float* pkq = ws + 3072;
    const float* pkm = ws + 4096;
    float* params = ws + 5120;
    int t = threadIdx.x;
    float qs = 0.f, qq = 0.f, ks = 0.f, kq = 0.f;
    for (int i = t; i < 1024; i += 256) {
        qs += pqs[i]; qq += pqq[i]; ks += pks[i]; kq += pkq[i];
    }
    qs = wave_reduce_sum(qs);
    qq = wave_reduce_sum(qq);
    ks = wave_reduce_sum(ks);
    kq = wave_reduce_sum(kq);
    __shared__ float l[4][4];
    __shared__ float lab[2];
    int w = t >> 6, lane = t & 63;
    if (lane == 0) { l[w][0] = qs; l[w][1] = qq; l[w][2] = ks; l[w][3] = kq; }
    __syncthreads();
    if (t == 0) {
        float QS = 0.f, QQ = 0.f, KS = 0.f, KQ = 0.f;
        for (int i = 0; i < 4; ++i) { QS += l[i][0]; QQ += l[i][1]; KS += l[i][2]; KQ += l[i][3]; }
        const double M = (double)ELEMS;
        double varq = ((double)QQ - (double)QS * (double)QS / M) / (M - 1.0);
        double vark = ((double)KQ - (double)KS * (double)KS / M) / (M - 1.0);
        const double A = 0.14855178144710912;
        const double B = -0.35487039130661086;
        double st2 = (varq * vark - B) / (2.0 * A);
        float alpha = (float)sqrt(st2 / varq);
        float beta  = (float)sqrt(st2 / vark);
        params[0] = alpha; params[1] = beta;
        lab[0] = alpha; lab[1] = beta;
    }
    __syncthreads();
    if (t < 64) {
        float m = -1e30f;
        for (int i = 0; i < 16; ++i) m = fmaxf(m, pkm[t * 16 + i]);
        params[2 + t] = lab[1] * m;
    }
}

// ---------------- Kernel 3: Kexp sums: Ksum[d], KV[d][e] -----------------------
__global__ __launch_bounds__(256) void kv_kernel(const float* __restrict__ k,
                                                 const float* __restrict__ v,
                                                 const float* __restrict__ params,
                                                 float* __restrict__ Ksum,
                                                 float* __restrict__ KV) {
    int t = threadIdx.x;
    int head = blockIdx.x >> 4;
    int chunk = blockIdx.x & 15;
    float beta = params[1];
    float kms = params[2 + head];
    __shared__ __align__(16) float lk[32][64];
    __shared__ __align__(16) float lv[32][64];
    int dg = t >> 4, eg = t & 15;
    float acc[4][4] = {};
    float ksacc[4] = {};
    long rowbase = (long)head * SEQ + chunk * 256;
    for (int sc = 0; sc < 8; ++sc) {
        long off = (rowbase + sc * 32) * DIM;
        const float4* k4 = (const float4*)(k + off);
        const float4* v4 = (const float4*)(v + off);
#pragma unroll
        for (int it = 0; it < 2; ++it) {
            int idx = it * 256 + t;
            float4 kk = k4[idx];
            float4 e;
            e.x = __expf(beta * kk.x - kms);
            e.y = __expf(beta * kk.y - kms);
            e.z = __expf(beta * kk.z - kms);
            e.w = __expf(beta * kk.w - kms);
            ((float4*)lk)[idx] = e;
            ((float4*)lv)[idx] = v4[idx];
        }
        __syncthreads();
#pragma unroll
        for (int r = 0; r < 32; ++r) {
            float4 kd = *(const float4*)&lk[r][dg * 4];
            float4 vv = *(const float4*)&lv[r][eg * 4];
            float ka[4] = {kd.x, kd.y, kd.z, kd.w};
            float vb[4] = {vv.x, vv.y, vv.z, vv.w};
#pragma unroll
            for (int i = 0; i < 4; ++i)
#pragma unroll
                for (int j = 0; j < 4; ++j) acc[i][j] += ka[i] * vb[j];
            if (eg == 0) {
#pragma unroll
                for (int i = 0; i < 4; ++i) ksacc[i] += ka[i];
            }
        }
        __syncthreads();
    }
    float* KVh = KV + head * (DIM * DIM);
#pragma unroll
    for (int i = 0; i < 4; ++i)
#pragma unroll
        for (int j = 0; j < 4; ++j)
            atomicAdd(&KVh[(dg * 4 + i) * DIM + eg * 4 + j], acc[i][j]);
    if (eg == 0) {
#pragma unroll
        for (int i = 0; i < 4; ++i) atomicAdd(&Ksum[head * DIM + dg * 4 + i], ksacc[i]);
    }
}

// ---------------- Kernel 4: fused block-diag attention + LLN epilogue ----------
__global__ __launch_bounds__(256) void fused_kernel(const float* __restrict__ q,
                                                    const float* __restrict__ k,
                                                    const float* __restrict__ v,
                                                    const float* __restrict__ params,
                                                    const float* __restrict__ Ksum,
                                                    const float* __restrict__ KV,
                                                    float* __restrict__ out) {
    constexpr int LDW = 68;  // stride padding: owned rows differ by 4 -> 2-way conflicts only
    __shared__ __align__(16) float lq[64][LDW];   // raw q -> Qexp (in place)
    __shared__ __align__(16) float lk[64][LDW];   // raw k -> probs (in place)
    __shared__ __align__(16) float lv[64][LDW];
    __shared__ __align__(16) float lkv[64][LDW];
    __shared__ __align__(16) float lksum[64];
    __shared__ float lqmax[64];
    __shared__ float lsinv[64];

    int t = threadIdx.x;
    int head = blockIdx.x >> 6;
    int rb = blockIdx.x & 63;
    long base = ((long)head * SEQ + rb * 64) * DIM;
    const float4* q4 = (const float4*)(q + base);
    const float4* k4 = (const float4*)(k + base);
    const float4* v4 = (const float4*)(v + base);
    const float4* kv4 = (const float4*)(KV + head * (DIM * DIM));

#pragma unroll
    for (int it = 0; it < 4; ++it) {
        int idx = it * 256 + t;
        int r = idx >> 4, c4 = idx & 15;
        *(float4*)&lq[r][c4 * 4] = q4[idx];
        *(float4*)&lk[r][c4 * 4] = k4[idx];
        *(float4*)&lv[r][c4 * 4] = v4[idx];
        *(float4*)&lkv[r][c4 * 4] = kv4[idx];
    }
    if (t < 16) *(float4*)&lksum[t * 4] = ((const float4*)(Ksum + head * DIM))[t];
    float alpha = params[0];
    __syncthreads();

    // P1: row maxes of q, and block-diag scores
    if (t < 64) {
        float m = -1e30f;
#pragma unroll
        for (int d4 = 0; d4 < 16; ++d4) {
            float4 x = *(const float4*)&lq[t][d4 * 4];
            m = fmaxf(m, fmaxf(fmaxf(x.x, x.y), fmaxf(x.z, x.w)));
        }
        lqmax[t] = m;
    }
    int rg = t >> 4, cg = t & 15;
    float s[4][4] = {};
#pragma unroll
    for (int d4 = 0; d4 < 16; ++d4) {
        float4 qa[4], kb[4];
#pragma unroll
        for (int a = 0; a < 4; ++a) qa[a] = *(const float4*)&lq[rg * 4 + a][d4 * 4];
#pragma unroll
        for (int b = 0; b < 4; ++b) kb[b] = *(const float4*)&lk[cg * 4 + b][d4 * 4];
#pragma unroll
        for (int a = 0; a < 4; ++a)
#pragma unroll
            for (int b = 0; b < 4; ++b)
                s[a][b] += qa[a].x * kb[b].x + qa[a].y * kb[b].y +
                           qa[a].z * kb[b].z + qa[a].w * kb[b].w;
    }
    __syncthreads();

    // P2: softmax (registers, 16-lane shuffles) -> probs into lk; Qexp into lq
    float p[4][4];
#pragma unroll
    for (int a = 0; a < 4; ++a) {
        float m = -1e30f;
#pragma unroll
        for (int b = 0; b < 4; ++b) { s[a][b] *= 0.125f; m = fmaxf(m, s[a][b]); }
#pragma unroll
        for (int msk = 8; msk >= 1; msk >>= 1) m = fmaxf(m, __shfl_xor(m, msk));
        float sum = 0.f;
#pragma unroll
        for (int b = 0; b < 4; ++b) { p[a][b] = __expf(s[a][b] - m); sum += p[a][b]; }
#pragma unroll
        for (int msk = 8; msk >= 1; msk >>= 1) sum += __shfl_xor(sum, msk);
        float inv = 1.f / sum;
#pragma unroll
        for (int b = 0; b < 4; ++b) p[a][b] *= inv;
    }
#pragma unroll
    for (int a = 0; a < 4; ++a)
#pragma unroll
        for (int b = 0; b < 4; ++b) lk[rg * 4 + a][cg * 4 + b] = p[a][b];
#pragma unroll
    for (int a = 0; a < 4; ++a) {
        int i = rg * 4 + a;
        float am = alpha * lqmax[i];
        float4 x = *(const float4*)&lq[i][cg * 4];
        x.x = __expf(alpha * x.x - am);
        x.y = __expf(alpha * x.y - am);
        x.z = __expf(alpha * x.z - am);
        x.w = __expf(alpha * x.w - am);
        *(float4*)&lq[i][cg * 4] = x;
    }
    __syncthreads();

    // P3: diag = probs @ v ; S = dot(Qexp, Ksum)
    float o[4][4] = {};
#pragma unroll
    for (int j4 = 0; j4 < 16; ++j4) {
        float4 pa[4], vb[4];
#pragma unroll
        for (int a = 0; a < 4; ++a) pa[a] = *(const float4*)&lk[rg * 4 + a][j4 * 4];
#pragma unroll
        for (int c = 0; c < 4; ++c) vb[c] = *(const float4*)&lv[j4 * 4 + c][cg * 4];
#pragma unroll
        for (int a = 0; a < 4; ++a) {
            float pav[4] = {pa[a].x, pa[a].y, pa[a].z, pa[a].w};
#pragma unroll
            for (int c = 0; c < 4; ++c) {
                float vbc[4] = {vb[c].x, vb[c].y, vb[c].z, vb[c].w};
#pragma unroll
                for (int b = 0; b < 4; ++b) o[a][b] += pav[c] * vbc[b];
            }
        }
    }
    if (t < 64) {
        float ssum = 0.f;
#pragma unroll
        for (int d4 = 0; d4 < 16; ++d4) {
            float4 qq = *(const float4*)&lq[t][d4 * 4];
            float4 ksv = *(const float4*)&lksum[d4 * 4];
            ssum += qq.x * ksv.x + qq.y * ksv.y + qq.z * ksv.z + qq.w * ksv.w;
        }
        lsinv[t] = 1.f / (ssum + 1e-8f);
    }
    __syncthreads();

    // P4: lln = Qexp @ KV * Sinv ; out = 0.5*(lln + diag)
    float acc[4][4] = {};
#pragma unroll
    for (int d4 = 0; d4 < 16; ++d4) {
        float4 qa[4], kvb[4];
#pragma unroll
        for (int a = 0; a < 4; ++a) qa[a] = *(const float4*)&lq[rg * 4 + a][d4 * 4];
#pragma unroll
        for (int c = 0; c < 4; ++c) kvb[c] = *(const float4*)&lkv[d4 * 4 + c][cg * 4];
#pragma unroll
        for (int a = 0; a < 4; ++a) {
            float qv[4] = {qa[a].x, qa[a].y, qa[a].z, qa[a].w};
#pragma unroll
            for (int c = 0; c < 4; ++c) {
                float kvc[4] = {kvb[c].x, kvb[c].y, kvb[c].z, kvb[c].w};
#pragma unroll
                for (int b = 0; b < 4; ++b) acc[a][b] += qv[c] * kvc[b];
            }
        }
    }
    float* outp = out + base;
#pragma unroll
    for (int a = 0; a < 4; ++a) {
        int i = rg * 4 + a;
        float si = lsinv[i];
        float4 r;
        r.x = 0.5f * (acc[a][0] * si + o[a][0]);
        r.y = 0.5f * (acc[a][1] * si + o[a][1]);
        r.z = 0.5f * (acc[a][2] * si + o[a][2]);
        r.w = 0.5f * (acc[a][3] * si + o[a][3]);
        *(float4*)&outp[i * DIM + cg * 4] = r;
    }
}

extern "C" void kernel_launch(void* const* d_in, const int* in_sizes, int n_in,
                              void* d_out, int out_size, void* d_ws, size_t ws_size,
                              hipStream_t stream) {
    const float* q = (const float*)d_in[0];
    const float* k = (const float*)d_in[1];
    const float* v = (const float*)d_in[2];
    float* out = (float*)d_out;
    float* ws = (float*)d_ws;
    float* params = ws + 5120;
    float* Ksum = ws + 6144;
    float* KV = ws + 10240;

    // zero the accumulators (ws is poisoned with 0xAA before every launch)
    hipMemsetAsync((void*)(ws + 6144), 0, (4096 + 262144) * sizeof(float), stream);

    reduce_stats<<<1024, 256, 0, stream>>>(q, ws, ws + 1024, nullptr);
    reduce_stats<<<1024, 256, 0, stream>>>(k, ws + 2048, ws + 3072, ws + 4096);
    compute_params<<<1, 256, 0, stream>>>(ws);
    kv_kernel<<<1024, 256, 0, stream>>>(k, v, params, Ksum, KV);
    fused_kernel<<<4096, 256, 0, stream>>>(q, k, v, params, Ksum, KV, out);
}

// Round 2
// 322.031 us; speedup vs baseline: 2.0112x; 2.0112x over previous
//
#include <hip/hip_runtime.h>
#include <math.h>

#define SEQ    4096
#define DIM    64
#define NHEADS 64
#define ELEMS  (NHEADS * SEQ * DIM)

typedef __attribute__((ext_vector_type(8))) short short8;
typedef __attribute__((ext_vector_type(4))) float f32x4;

#define MFMA16(a, b, c) __builtin_amdgcn_mfma_f32_16x16x32_bf16((a), (b), (c), 0, 0, 0)

__device__ __forceinline__ short f2b(float f) {
    union { float f; unsigned u; } x; x.f = f;
    return (short)((x.u + 0x7FFFu + ((x.u >> 16) & 1u)) >> 16);
}

// ---------------- Kernel 1: stats for q and k in one launch --------------------
// ws: [0,1024) qsum [1024,2048) qsumsq [2048,3072) ksum [3072,4096) ksumsq [4096,5120) kmax
__global__ __launch_bounds__(256) void reduce_stats(const float* __restrict__ q,
                                                    const float* __restrict__ kk,
                                                    float* __restrict__ ws) {
    int bid = blockIdx.x;
    int t = threadIdx.x;
    int isk = bid >> 10;          // 0: q, 1: k
    int b = bid & 1023;
    const float4* x4 = (const float4*)((isk ? kk : q) + (long)b * 16384);
    float s = 0.f, sq = 0.f, mx = -1e30f;
#pragma unroll
    for (int it = 0; it < 16; ++it) {
        float4 v = x4[it * 256 + t];
        s += v.x + v.y + v.z + v.w;
        sq += v.x * v.x + v.y * v.y + v.z * v.z + v.w * v.w;
        mx = fmaxf(mx, fmaxf(fmaxf(v.x, v.y), fmaxf(v.z, v.w)));
    }
#pragma unroll
    for (int m = 32; m > 0; m >>= 1) {
        s += __shfl_xor(s, m);
        sq += __shfl_xor(sq, m);
        mx = fmaxf(mx, __shfl_xor(mx, m));
    }
    __shared__ float ls[4], lsq[4], lm[4];
    int w = t >> 6, lane = t & 63;
    if (lane == 0) { ls[w] = s; lsq[w] = sq; lm[w] = mx; }
    __syncthreads();
    if (t == 0) {
        float S = 0.f, SQ = 0.f, M = -1e30f;
        for (int i = 0; i < 4; ++i) { S += ls[i]; SQ += lsq[i]; M = fmaxf(M, lm[i]); }
        ws[isk * 2048 + b] = S;
        ws[isk * 2048 + 1024 + b] = SQ;
        if (isk) ws[4096 + b] = M;
    }
}

// ---------------- Kernel 2: alpha/beta + per-head beta*kmax --------------------
__global__ __launch_bounds__(256) void compute_params(float* __restrict__ ws) {
    const float* pqs = ws;
    const float* pqq = ws + 1024;
    const float* pks = ws + 2048;
    const float* pkq = ws + 3072;
    const float* pkm = ws + 4096;
    float* params = ws + 5120;
    int t = threadIdx.x;
    float qs = 0.f, qq = 0.f, ks = 0.f, kq = 0.f;
    for (int i = t; i < 1024; i += 256) {
        qs += pqs[i]; qq += pqq[i]; ks += pks[i]; kq += pkq[i];
    }
#pragma unroll
    for (int m = 32; m > 0; m >>= 1) {
        qs += __shfl_xor(qs, m); qq += __shfl_xor(qq, m);
        ks += __shfl_xor(ks, m); kq += __shfl_xor(kq, m);
    }
    __shared__ float l[4][4];
    __shared__ float lab[2];
    int w = t >> 6, lane = t & 63;
    if (lane == 0) { l[w][0] = qs; l[w][1] = qq; l[w][2] = ks; l[w][3] = kq; }
    __syncthreads();
    if (t == 0) {
        float QS = 0.f, QQ = 0.f, KS = 0.f, KQ = 0.f;
        for (int i = 0; i < 4; ++i) { QS += l[i][0]; QQ += l[i][1]; KS += l[i][2]; KQ += l[i][3]; }
        const double M = (double)ELEMS;
        double varq = ((double)QQ - (double)QS * (double)QS / M) / (M - 1.0);
        double vark = ((double)KQ - (double)KS * (double)KS / M) / (M - 1.0);
        const double A = 0.14855178144710912;
        const double B = -0.35487039130661086;
        double st2 = (varq * vark - B) / (2.0 * A);
        float alpha = (float)sqrt(st2 / varq);
        float beta  = (float)sqrt(st2 / vark);
        params[0] = alpha; params[1] = beta;
        lab[0] = alpha; lab[1] = beta;
    }
    __syncthreads();
    if (t < 64) {
        float m = -1e30f;
        for (int i = 0; i < 16; ++i) m = fmaxf(m, pkm[t * 16 + i]);
        params[2 + t] = lab[1] * m;
    }
}

// ---------------- Kernel 3: Ksum[d], KVt[e][d] = (Kexp^T V)^T via MFMA ---------
// 16 K-parts per head; 8 chunks of 32 seq rows per part.
__global__ __launch_bounds__(256, 4) void kv_kernel(const float* __restrict__ k,
                                                    const float* __restrict__ v,
                                                    const float* __restrict__ params,
                                                    float* __restrict__ Ksum,
                                                    float* __restrict__ KVt) {
    __shared__ short kt[64][40];   // kt[d][r]  (Kexp^T), stride 80B (16B aligned)
    __shared__ short vt[64][40];   // vt[e][r]  (V^T)
    int t = threadIdx.x;
    int head = blockIdx.x >> 4, part = blockIdx.x & 15;
    float beta = params[1], kms = params[2 + head];
    int rp = t & 15, cg = t >> 4;          // row-pair 0..15, col-group 0..15
    int w = t >> 6, lane = t & 63;
    int am = lane & 15, ak8 = (lane >> 4) * 8;
    long rowbase = (long)head * SEQ + part * 256;
    f32x4 acc[4];
#pragma unroll
    for (int i = 0; i < 4; ++i) acc[i] = (f32x4)0.f;
    float ksc[4] = {0.f, 0.f, 0.f, 0.f};
    for (int ch = 0; ch < 8; ++ch) {
        long r0 = rowbase + ch * 32 + rp * 2;
        const float* kp = k + r0 * DIM + cg * 4;
        const float* vp = v + r0 * DIM + cg * 4;
        float4 ka = *(const float4*)kp;
        float4 kb2 = *(const float4*)(kp + DIM);
        float4 va = *(const float4*)vp;
        float4 vb2 = *(const float4*)(vp + DIM);
        float ea[4] = {__expf(beta * ka.x - kms), __expf(beta * ka.y - kms),
                       __expf(beta * ka.z - kms), __expf(beta * ka.w - kms)};
        float eb[4] = {__expf(beta * kb2.x - kms), __expf(beta * kb2.y - kms),
                       __expf(beta * kb2.z - kms), __expf(beta * kb2.w - kms)};
        float va_[4] = {va.x, va.y, va.z, va.w};
        float vb_[4] = {vb2.x, vb2.y, vb2.z, vb2.w};
        if (ch) __syncthreads();   // previous chunk's reads done
#pragma unroll
        for (int j = 0; j < 4; ++j) {
            ksc[j] += ea[j] + eb[j];
            unsigned pk = (unsigned)(unsigned short)f2b(ea[j]) |
                          ((unsigned)(unsigned short)f2b(eb[j]) << 16);
            *(unsigned*)&kt[cg * 4 + j][rp * 2] = pk;
            unsigned pv = (unsigned)(unsigned short)f2b(va_[j]) |
                          ((unsigned)(unsigned short)f2b(vb_[j]) << 16);
            *(unsigned*)&vt[cg * 4 + j][rp * 2] = pv;
        }
        __syncthreads();
        short8 af = *(const short8*)&kt[w * 16 + am][ak8];
#pragma unroll
        for (int nt = 0; nt < 4; ++nt) {
            short8 bf = *(const short8*)&vt[nt * 16 + am][ak8];
            acc[nt] = MFMA16(af, bf, acc[nt]);
        }
    }
    float* KVh = KVt + head * 4096;
#pragma unroll
    for (int nt = 0; nt < 4; ++nt)
#pragma unroll
        for (int r = 0; r < 4; ++r) {
            int d = w * 16 + (lane >> 4) * 4 + r;
            int e = nt * 16 + am;
            atomicAdd(&KVh[e * 64 + d], acc[nt][r]);
        }
#pragma unroll
    for (int m = 1; m < 16; m <<= 1)
#pragma unroll
        for (int j = 0; j < 4; ++j) ksc[j] += __shfl_xor(ksc[j], m);
    if (rp == 0) {
#pragma unroll
        for (int j = 0; j < 4; ++j) atomicAdd(&Ksum[head * 64 + cg * 4 + j], ksc[j]);
    }
}

// ---------------- Kernel 4: fused block-diag attn + LLN epilogue (MFMA) --------
__global__ __launch_bounds__(256, 4) void fused_kernel(const float* __restrict__ q,
                                                       const float* __restrict__ k,
                                                       const float* __restrict__ v,
                                                       const float* __restrict__ params,
                                                       const float* __restrict__ Ksum,
                                                       const float* __restrict__ KVt,
                                                       float* __restrict__ out) {
    constexpr int LD = 72;  // shorts; 144B stride (16B aligned, ~2-way banks)
    __shared__ short qb[64][LD];    // raw q bf16 -> Qexp bf16
    __shared__ short kb[64][LD];    // raw k bf16 -> probs bf16
    __shared__ short vtb[64][LD];   // V^T
    __shared__ short kvb[64][LD];   // KVt rows: kvb[e][d]
    __shared__ float lksum[64];
    __shared__ float lqmax[64];
    __shared__ float lsinv[64];

    int t = threadIdx.x;
    int head = blockIdx.x >> 6, rb = blockIdx.x & 63;
    long base = ((long)head * SEQ + rb * 64) * DIM;
    float alpha = params[0];
    int w = t >> 6, lane = t & 63;
    int am = lane & 15, ak8 = (lane >> 4) * 8;

    // ---- stage q,k,KVt (coalesced) + q row-max; keep raw q in regs ----
    float4 qraw[4];
#pragma unroll
    for (int it = 0; it < 4; ++it) {
        int idx = it * 256 + t;
        int r = idx >> 4, c4 = idx & 15;
        float4 qv = *(const float4*)(q + base + r * DIM + c4 * 4);
        float4 kv2 = *(const float4*)(k + base + r * DIM + c4 * 4);
        float4 kvv = *(const float4*)(KVt + head * 4096 + r * DIM + c4 * 4);
        qraw[it] = qv;
        *(unsigned*)&qb[r][c4 * 4] = (unsigned)(unsigned short)f2b(qv.x) | ((unsigned)(unsigned short)f2b(qv.y) << 16);
        *(unsigned*)&qb[r][c4 * 4 + 2] = (unsigned)(unsigned short)f2b(qv.z) | ((unsigned)(unsigned short)f2b(qv.w) << 16);
        *(unsigned*)&kb[r][c4 * 4] = (unsigned)(unsigned short)f2b(kv2.x) | ((unsigned)(unsigned short)f2b(kv2.y) << 16);
        *(unsigned*)&kb[r][c4 * 4 + 2] = (unsigned)(unsigned short)f2b(kv2.z) | ((unsigned)(unsigned short)f2b(kv2.w) << 16);
        *(unsigned*)&kvb[r][c4 * 4] = (unsigned)(unsigned short)f2b(kvv.x) | ((unsigned)(unsigned short)f2b(kvv.y) << 16);
        *(unsigned*)&kvb[r][c4 * 4 + 2] = (unsigned)(unsigned short)f2b(kvv.z) | ((unsigned)(unsigned short)f2b(kvv.w) << 16);
        float m = fmaxf(fmaxf(qv.x, qv.y), fmaxf(qv.z, qv.w));
#pragma unroll
        for (int msk = 8; msk >= 1; msk >>= 1) m = fmaxf(m, __shfl_xor(m, msk));
        if (c4 == 0) lqmax[r] = m;
    }
    // ---- stage V^T via pair-packed transpose (bank-conflict-free) ----
#pragma unroll
    for (int it2 = 0; it2 < 2; ++it2) {
        int u = it2 * 256 + t;
        int rp = u & 31, cg = u >> 5;
        const float* vp = v + base + (rp * 2) * DIM + cg * 4;
        float4 va = *(const float4*)vp;
        float4 vb2 = *(const float4*)(vp + DIM);
        float va_[4] = {va.x, va.y, va.z, va.w};
        float vb_[4] = {vb2.x, vb2.y, vb2.z, vb2.w};
#pragma unroll
        for (int j = 0; j < 4; ++j) {
            unsigned pv = (unsigned)(unsigned short)f2b(va_[j]) |
                          ((unsigned)(unsigned short)f2b(vb_[j]) << 16);
            *(unsigned*)&vtb[cg * 4 + j][rp * 2] = pv;
        }
    }
    if (t < 16) *(float4*)&lksum[t * 4] = *(const float4*)(Ksum + head * DIM + t * 4);
    __syncthreads();

    // ---- scores = (q k^T)/8 via MFMA ----
    short8 a0 = *(const short8*)&qb[w * 16 + am][ak8];
    short8 a1 = *(const short8*)&qb[w * 16 + am][32 + ak8];
    f32x4 sc[4];
#pragma unroll
    for (int i = 0; i < 4; ++i) sc[i] = (f32x4)0.f;
#pragma unroll
    for (int nt = 0; nt < 4; ++nt) {
        short8 b0 = *(const short8*)&kb[nt * 16 + am][ak8];
        short8 b1 = *(const short8*)&kb[nt * 16 + am][32 + ak8];
        sc[nt] = MFMA16(a0, b0, sc[nt]);
        sc[nt] = MFMA16(a1, b1, sc[nt]);
    }
    // ---- softmax over 64 cols (4 tiles in-reg, 16-lane shuffles) ----
#pragma unroll
    for (int r = 0; r < 4; ++r) {
        float m = -1e30f;
#pragma unroll
        for (int nt = 0; nt < 4; ++nt) { sc[nt][r] *= 0.125f; m = fmaxf(m, sc[nt][r]); }
#pragma unroll
        for (int msk = 8; msk >= 1; msk >>= 1) m = fmaxf(m, __shfl_xor(m, msk));
        float sum = 0.f;
#pragma unroll
        for (int nt = 0; nt < 4; ++nt) { float e = __expf(sc[nt][r] - m); sc[nt][r] = e; sum += e; }
#pragma unroll
        for (int msk = 8; msk >= 1; msk >>= 1) sum += __shfl_xor(sum, msk);
        float inv = 1.f / sum;
#pragma unroll
        for (int nt = 0; nt < 4; ++nt) sc[nt][r] *= inv;
    }
    // ---- Qexp from raw f32 q in regs; S = Qexp . Ksum ----
    unsigned qe[4][2];
#pragma unroll
    for (int it = 0; it < 4; ++it) {
        int idx = it * 256 + t;
        int r = idx >> 4, c4 = idx & 15;
        float am_ = alpha * lqmax[r];
        float e0 = __expf(alpha * qraw[it].x - am_);
        float e1 = __expf(alpha * qraw[it].y - am_);
        float e2 = __expf(alpha * qraw[it].z - am_);
        float e3 = __expf(alpha * qraw[it].w - am_);
        float4 ks4 = *(const float4*)&lksum[c4 * 4];
        float dot = e0 * ks4.x + e1 * ks4.y + e2 * ks4.z + e3 * ks4.w;
#pragma unroll
        for (int msk = 8; msk >= 1; msk >>= 1) dot += __shfl_xor(dot, msk);
        if (c4 == 0) lsinv[r] = 1.f / (dot + 1e-8f);
        qe[it][0] = (unsigned)(unsigned short)f2b(e0) | ((unsigned)(unsigned short)f2b(e1) << 16);
        qe[it][1] = (unsigned)(unsigned short)f2b(e2) | ((unsigned)(unsigned short)f2b(e3) << 16);
    }
    __syncthreads();   // all reads of qb/kb complete
    // ---- write probs -> kb, Qexp -> qb ----
#pragma unroll
    for (int it = 0; it < 4; ++it) {
        int idx = it * 256 + t;
        int r = idx >> 4, c4 = idx & 15;
        *(unsigned*)&qb[r][c4 * 4] = qe[it][0];
        *(unsigned*)&qb[r][c4 * 4 + 2] = qe[it][1];
    }
#pragma unroll
    for (int nt = 0; nt < 4; ++nt)
#pragma unroll
        for (int r = 0; r < 4; ++r)
            kb[w * 16 + (lane >> 4) * 4 + r][nt * 16 + am] = f2b(sc[nt][r]);
    __syncthreads();

    // ---- diag = P @ V ; lln = Qexp @ KV ----
    short8 pa0 = *(const short8*)&kb[w * 16 + am][ak8];
    short8 pa1 = *(const short8*)&kb[w * 16 + am][32 + ak8];
    short8 qa0 = *(const short8*)&qb[w * 16 + am][ak8];
    short8 qa1 = *(const short8*)&qb[w * 16 + am][32 + ak8];
    f32x4 o[4], acc[4];
#pragma unroll
    for (int i = 0; i < 4; ++i) { o[i] = (f32x4)0.f; acc[i] = (f32x4)0.f; }
#pragma unroll
    for (int nt = 0; nt < 4; ++nt) {
        short8 vb0 = *(const short8*)&vtb[nt * 16 + am][ak8];
        short8 vb1 = *(const short8*)&vtb[nt * 16 + am][32 + ak8];
        o[nt] = MFMA16(pa0, vb0, o[nt]);
        o[nt] = MFMA16(pa1, vb1, o[nt]);
        short8 kb0 = *(const short8*)&kvb[nt * 16 + am][ak8];
        short8 kb1 = *(const short8*)&kvb[nt * 16 + am][32 + ak8];
        acc[nt] = MFMA16(qa0, kb0, acc[nt]);
        acc[nt] = MFMA16(qa1, kb1, acc[nt]);
    }
    // ---- epilogue: out = 0.5*(lln/S + diag) ----
#pragma unroll
    for (int r = 0; r < 4; ++r) {
        int row = w * 16 + (lane >> 4) * 4 + r;
        float si = lsinv[row];
#pragma unroll
        for (int nt = 0; nt < 4; ++nt)
            out[base + (long)row * DIM + nt * 16 + am] = 0.5f * (acc[nt][r] * si + o[nt][r]);
    }
}

extern "C" void kernel_launch(void* const* d_in, const int* in_sizes, int n_in,
                              void* d_out, int out_size, void* d_ws, size_t ws_size,
                              hipStream_t stream) {
    const float* q = (const float*)d_in[0];
    const float* k = (const float*)d_in[1];
    const float* v = (const float*)d_in[2];
    float* out = (float*)d_out;
    float* ws = (float*)d_ws;
    float* params = ws + 5120;
    float* Ksum = ws + 6144;          // [64][64]
    float* KVt = ws + 10240;          // [64 heads][64 e][64 d]

    hipMemsetAsync((void*)(ws + 6144), 0, (4096 + 262144) * sizeof(float), stream);

    reduce_stats<<<2048, 256, 0, stream>>>(q, k, ws);
    compute_params<<<1, 256, 0, stream>>>(ws);
    kv_kernel<<<1024, 256, 0, stream>>>(k, v, params, Ksum, KVt);
    fused_kernel<<<4096, 256, 0, stream>>>(q, k, v, params, Ksum, KVt, out);
}

// Round 3
// 267.501 us; speedup vs baseline: 2.4212x; 1.2038x over previous
//
#include <hip/hip_runtime.h>
#include <math.h>

#define SEQ    4096
#define DIM    64
#define NHEADS 64
#define ELEMS  (NHEADS * SEQ * DIM)

typedef __attribute__((ext_vector_type(8))) short short8;
typedef __attribute__((ext_vector_type(4))) short short4v;
typedef __attribute__((ext_vector_type(4))) float f32x4;

#define MFMA16(a, b, c) __builtin_amdgcn_mfma_f32_16x16x32_bf16((a), (b), (c), 0, 0, 0)

__device__ __forceinline__ short f2b(float f) {
    union { float f; unsigned u; } x; x.f = f;
    return (short)((x.u + 0x7FFFu + ((x.u >> 16) & 1u)) >> 16);
}

// ws layout (floats):
//  [0,1024) qsum | [1024,2048) qsumsq | [2048,3072) ksum | [3072,4096) ksumsq
//  [4096,5120) kmax | [5120,5248) params: [0]=alpha [1]=beta [2+h]=beta*kmax[h]
//  [8192,270336)  KVt final   [64 h][64 e][64 d]
//  [270336,274432) Ksum final [64 h][64 d]
//  [274432,2371584) kvpart    [8 p][64 h][64 e][64 d]
//  [2371584,2404352) kspart   [8 p][64 h][64 d]

// ---------------- Kernel 1: stats for q and k --------------------------------
__global__ __launch_bounds__(256) void reduce_stats(const float* __restrict__ q,
                                                    const float* __restrict__ kk,
                                                    float* __restrict__ ws) {
    int bid = blockIdx.x;
    int t = threadIdx.x;
    int isk = bid >> 10;
    int b = bid & 1023;
    const float4* x4 = (const float4*)((isk ? kk : q) + (long)b * 16384);
    float s = 0.f, sq = 0.f, mx = -1e30f;
#pragma unroll
    for (int it = 0; it < 16; ++it) {
        float4 v = x4[it * 256 + t];
        s += v.x + v.y + v.z + v.w;
        sq += v.x * v.x + v.y * v.y + v.z * v.z + v.w * v.w;
        mx = fmaxf(mx, fmaxf(fmaxf(v.x, v.y), fmaxf(v.z, v.w)));
    }
#pragma unroll
    for (int m = 32; m > 0; m >>= 1) {
        s += __shfl_xor(s, m);
        sq += __shfl_xor(sq, m);
        mx = fmaxf(mx, __shfl_xor(mx, m));
    }
    __shared__ float ls[4], lsq[4], lm[4];
    int w = t >> 6, lane = t & 63;
    if (lane == 0) { ls[w] = s; lsq[w] = sq; lm[w] = mx; }
    __syncthreads();
    if (t == 0) {
        float S = 0.f, SQ = 0.f, M = -1e30f;
        for (int i = 0; i < 4; ++i) { S += ls[i]; SQ += lsq[i]; M = fmaxf(M, lm[i]); }
        ws[isk * 2048 + b] = S;
        ws[isk * 2048 + 1024 + b] = SQ;
        if (isk) ws[4096 + b] = M;
    }
}

// ---------------- Kernel 2: alpha/beta + per-head beta*kmax ------------------
__global__ __launch_bounds__(256) void compute_params(float* __restrict__ ws) {
    const float* pqs = ws;
    const float* pqq = ws + 1024;
    const float* pks = ws + 2048;
    const float* pkq = ws + 3072;
    const float* pkm = ws + 4096;
    float* params = ws + 5120;
    int t = threadIdx.x;
    float qs = 0.f, qq = 0.f, ks = 0.f, kq = 0.f;
    for (int i = t; i < 1024; i += 256) {
        qs += pqs[i]; qq += pqq[i]; ks += pks[i]; kq += pkq[i];
    }
#pragma unroll
    for (int m = 32; m > 0; m >>= 1) {
        qs += __shfl_xor(qs, m); qq += __shfl_xor(qq, m);
        ks += __shfl_xor(ks, m); kq += __shfl_xor(kq, m);
    }
    __shared__ float l[4][4];
    __shared__ float lab[2];
    int w = t >> 6, lane = t & 63;
    if (lane == 0) { l[w][0] = qs; l[w][1] = qq; l[w][2] = ks; l[w][3] = kq; }
    __syncthreads();
    if (t == 0) {
        float QS = 0.f, QQ = 0.f, KS = 0.f, KQ = 0.f;
        for (int i = 0; i < 4; ++i) { QS += l[i][0]; QQ += l[i][1]; KS += l[i][2]; KQ += l[i][3]; }
        const double M = (double)ELEMS;
        double varq = ((double)QQ - (double)QS * (double)QS / M) / (M - 1.0);
        double vark = ((double)KQ - (double)KS * (double)KS / M) / (M - 1.0);
        const double A = 0.14855178144710912;
        const double B = -0.35487039130661086;
        double st2 = (varq * vark - B) / (2.0 * A);
        float alpha = (float)sqrt(st2 / varq);
        float beta  = (float)sqrt(st2 / vark);
        params[0] = alpha; params[1] = beta;
        lab[0] = alpha; lab[1] = beta;
    }
    __syncthreads();
    if (t < 64) {
        float m = -1e30f;
        for (int i = 0; i < 16; ++i) m = fmaxf(m, pkm[t * 16 + i]);
        params[2 + t] = lab[1] * m;
    }
}

// ---------------- Kernel 3: Kexp^T V partials via MFMA -----------------------
// 8 parts/head, 512 rows/part, 4 chunks of 128 rows, double-buffered LDS.
// kappa-permutation: row n (within chunk) -> kappa = 4*(n%32) + n/32, applied
// identically to kt and vt so the contraction is order-invariant.
__global__ __launch_bounds__(512, 4) void kv_kernel(const float* __restrict__ k,
                                                    const float* __restrict__ v,
                                                    const float* __restrict__ params,
                                                    float* __restrict__ kvpart,
                                                    float* __restrict__ kspart) {
    constexpr int LDK = 132;   // shorts per row (66 words): bank-optimal
    __shared__ short kt[2][64][LDK];
    __shared__ short vt[2][64][LDK];
    __shared__ float lksum[64];
    int t = threadIdx.x;
    int head = blockIdx.x >> 3, part = blockIdx.x & 7;
    float beta = params[1], kms = params[2 + head];
    int n0 = t >> 4, m = t & 15;
    if (t < 64) lksum[t] = 0.f;
    const float* kb_ = k + ((long)head * SEQ + part * 512) * DIM + m * 4;
    const float* vb_ = v + ((long)head * SEQ + part * 512) * DIM + m * 4;

    int w = t >> 6, lane = t & 63;
    int dblk = w >> 1, epair = w & 1;
    int am = lane & 15, q = lane >> 4;

    float kra[4][4], vra[4][4];
#pragma unroll
    for (int i = 0; i < 4; ++i) {
        long off = (long)(n0 + 32 * i) * DIM;
        float4 x = *(const float4*)(kb_ + off);
        float4 y = *(const float4*)(vb_ + off);
        kra[i][0] = x.x; kra[i][1] = x.y; kra[i][2] = x.z; kra[i][3] = x.w;
        vra[i][0] = y.x; vra[i][1] = y.y; vra[i][2] = y.z; vra[i][3] = y.w;
    }

    f32x4 acc[2];
    acc[0] = (f32x4)0.f; acc[1] = (f32x4)0.f;
    float ksc[4] = {0.f, 0.f, 0.f, 0.f};

    for (int c = 0; c < 4; ++c) {
        int buf = c & 1;
        // exp + pack + transposed LDS write (conflict-free by construction)
        float ek[4][4];
#pragma unroll
        for (int i = 0; i < 4; ++i)
#pragma unroll
            for (int j = 0; j < 4; ++j) {
                float e = __expf(beta * kra[i][j] - kms);
                ek[i][j] = e;
                ksc[j] += e;
            }
#pragma unroll
        for (int j = 0; j < 4; ++j) {
            short4v pk = {f2b(ek[0][j]), f2b(ek[1][j]), f2b(ek[2][j]), f2b(ek[3][j])};
            short4v pv = {f2b(vra[0][j]), f2b(vra[1][j]), f2b(vra[2][j]), f2b(vra[3][j])};
            *(short4v*)&kt[buf][4 * m + j][4 * n0] = pk;
            *(short4v*)&vt[buf][4 * m + j][4 * n0] = pv;
        }
        // prefetch next chunk (latency hides under barrier + MFMA phase)
        if (c < 3) {
#pragma unroll
            for (int i = 0; i < 4; ++i) {
                long off = (long)((c + 1) * 128 + n0 + 32 * i) * DIM;
                float4 x = *(const float4*)(kb_ + off);
                float4 y = *(const float4*)(vb_ + off);
                kra[i][0] = x.x; kra[i][1] = x.y; kra[i][2] = x.z; kra[i][3] = x.w;
                vra[i][0] = y.x; vra[i][1] = y.y; vra[i][2] = y.z; vra[i][3] = y.w;
            }
        }
        __syncthreads();
#pragma unroll
        for (int ks = 0; ks < 4; ++ks) {
            int k0 = ks * 32 + q * 8;
            short4v a0 = *(const short4v*)&kt[buf][dblk * 16 + am][k0];
            short4v a1 = *(const short4v*)&kt[buf][dblk * 16 + am][k0 + 4];
            short8 af = __builtin_shufflevector(a0, a1, 0, 1, 2, 3, 4, 5, 6, 7);
#pragma unroll
            for (int et = 0; et < 2; ++et) {
                int e = (epair * 2 + et) * 16 + am;
                short4v b0 = *(const short4v*)&vt[buf][e][k0];
                short4v b1 = *(const short4v*)&vt[buf][e][k0 + 4];
                short8 bf = __builtin_shufflevector(b0, b1, 0, 1, 2, 3, 4, 5, 6, 7);
                acc[et] = MFMA16(af, bf, acc[et]);
            }
        }
    }
    // Ksum: reduce over q-groups (lanes xor 16,32 share the same d-set)
#pragma unroll
    for (int j = 0; j < 4; ++j) {
        ksc[j] += __shfl_xor(ksc[j], 16);
        ksc[j] += __shfl_xor(ksc[j], 32);
    }
    if (q == 0) {
#pragma unroll
        for (int j = 0; j < 4; ++j) atomicAdd(&lksum[4 * m + j], ksc[j]);
    }
    // KV partial store (coalesced float4, no global atomics)
    float* kvp = kvpart + ((long)part * 64 + head) * 4096;
#pragma unroll
    for (int et = 0; et < 2; ++et) {
        int e = (epair * 2 + et) * 16 + am;
        float4 st;
        st.x = acc[et][0]; st.y = acc[et][1]; st.z = acc[et][2]; st.w = acc[et][3];
        *(float4*)&kvp[e * 64 + dblk * 16 + q * 4] = st;
    }
    __syncthreads();
    if (t < 64) kspart[((long)part * 64 + head) * 64 + t] = lksum[t];
}

// ---------------- Kernel 3b: sum the 8 partials ------------------------------
__global__ __launch_bounds__(256) void kv_reduce(const float* __restrict__ kvp,
                                                 const float* __restrict__ ksp,
                                                 float* __restrict__ KVt,
                                                 float* __restrict__ Ksum) {
    int b = blockIdx.x;
    int idx = b * 256 + threadIdx.x;
    if (b < 1024) {
        float s = 0.f;
#pragma unroll
        for (int p = 0; p < 8; ++p) s += kvp[p * 262144 + idx];
        KVt[idx] = s;
    } else {
        int i2 = idx - 262144;
        float s = 0.f;
#pragma unroll
        for (int p = 0; p < 8; ++p) s += ksp[p * 4096 + i2];
        Ksum[i2] = s;
    }
}

// ---------------- Kernel 4: fused block-diag attn + LLN epilogue -------------
__global__ __launch_bounds__(256, 4) void fused_kernel(const float* __restrict__ q,
                                                       const float* __restrict__ k,
                                                       const float* __restrict__ v,
                                                       const float* __restrict__ params,
                                                       const float* __restrict__ Ksum,
                                                       const float* __restrict__ KVt,
                                                       float* __restrict__ out) {
    constexpr int LD = 72;    // shorts, for qb/kb/kvb (identity-column tiles)
    constexpr int LDV = 68;   // shorts, for vtb (kappa-permuted columns)
    __shared__ short qb[64][LD];    // raw q bf16 -> Qexp bf16
    __shared__ short kb[64][LD];    // raw k bf16 -> probs bf16 (pi-permuted cols)
    __shared__ short kvb[64][LD];   // KVt rows: kvb[e][d]
    __shared__ short vtb[64][LDV];  // vtb[e][kappa], kappa = 4*(n%16)+n/16
    __shared__ float lksum[64];
    __shared__ float lqmax[64];
    __shared__ float lsinv[64];

    int t = threadIdx.x;
    int head = blockIdx.x >> 6, rb = blockIdx.x & 63;
    long base = ((long)head * SEQ + rb * 64) * DIM;
    float alpha = params[0];
    int w = t >> 6, lane = t & 63;
    int am = lane & 15, q16 = lane >> 4, ak8 = q16 * 8;

    // ---- stage q,k,KVt (coalesced) + q row-max; keep raw q in regs ----
    float4 qraw[4];
#pragma unroll
    for (int it = 0; it < 4; ++it) {
        int idx = it * 256 + t;
        int r = idx >> 4, c4 = idx & 15;
        float4 qv = *(const float4*)(q + base + r * DIM + c4 * 4);
        float4 kv2 = *(const float4*)(k + base + r * DIM + c4 * 4);
        float4 kvv = *(const float4*)(KVt + head * 4096 + r * DIM + c4 * 4);
        qraw[it] = qv;
        *(unsigned*)&qb[r][c4 * 4]     = (unsigned)(unsigned short)f2b(qv.x) | ((unsigned)(unsigned short)f2b(qv.y) << 16);
        *(unsigned*)&qb[r][c4 * 4 + 2] = (unsigned)(unsigned short)f2b(qv.z) | ((unsigned)(unsigned short)f2b(qv.w) << 16);
        *(unsigned*)&kb[r][c4 * 4]     = (unsigned)(unsigned short)f2b(kv2.x) | ((unsigned)(unsigned short)f2b(kv2.y) << 16);
        *(unsigned*)&kb[r][c4 * 4 + 2] = (unsigned)(unsigned short)f2b(kv2.z) | ((unsigned)(unsigned short)f2b(kv2.w) << 16);
        *(unsigned*)&kvb[r][c4 * 4]     = (unsigned)(unsigned short)f2b(kvv.x) | ((unsigned)(unsigned short)f2b(kvv.y) << 16);
        *(unsigned*)&kvb[r][c4 * 4 + 2] = (unsigned)(unsigned short)f2b(kvv.z) | ((unsigned)(unsigned short)f2b(kvv.w) << 16);
        float mq = fmaxf(fmaxf(qv.x, qv.y), fmaxf(qv.z, qv.w));
#pragma unroll
        for (int msk = 8; msk >= 1; msk >>= 1) mq = fmaxf(mq, __shfl_xor(mq, msk));
        if (c4 == 0) lqmax[r] = mq;
    }
    // ---- stage V^T with coalesced loads + kappa-interleave ----
    {
        float vva[4][4];
#pragma unroll
        for (int i = 0; i < 4; ++i) {
            int n = (t >> 4) + 16 * i;
            float4 x = *(const float4*)(v + base + (long)n * DIM + (t & 15) * 4);
            vva[i][0] = x.x; vva[i][1] = x.y; vva[i][2] = x.z; vva[i][3] = x.w;
        }
#pragma unroll
        for (int j = 0; j < 4; ++j) {
            short4v pv = {f2b(vva[0][j]), f2b(vva[1][j]), f2b(vva[2][j]), f2b(vva[3][j])};
            *(short4v*)&vtb[(t & 15) * 4 + j][4 * (t >> 4)] = pv;
        }
    }
    if (t < 16) *(float4*)&lksum[t * 4] = *(const float4*)(Ksum + head * DIM + t * 4);
    __syncthreads();

    // ---- scores = (q k^T)/8 via MFMA ----
    short8 a0 = *(const short8*)&qb[w * 16 + am][ak8];
    short8 a1 = *(const short8*)&qb[w * 16 + am][32 + ak8];
    f32x4 sc[4];
#pragma unroll
    for (int i = 0; i < 4; ++i) sc[i] = (f32x4)0.f;
#pragma unroll
    for (int nt = 0; nt < 4; ++nt) {
        short8 b0 = *(const short8*)&kb[nt * 16 + am][ak8];
        short8 b1 = *(const short8*)&kb[nt * 16 + am][32 + ak8];
        sc[nt] = MFMA16(a0, b0, sc[nt]);
        sc[nt] = MFMA16(a1, b1, sc[nt]);
    }
    // ---- softmax over 64 cols (in-reg, 16-lane shuffles) ----
#pragma unroll
    for (int r = 0; r < 4; ++r) {
        float mm = -1e30f;
#pragma unroll
        for (int nt = 0; nt < 4; ++nt) { sc[nt][r] *= 0.125f; mm = fmaxf(mm, sc[nt][r]); }
#pragma unroll
        for (int msk = 8; msk >= 1; msk >>= 1) mm = fmaxf(mm, __shfl_xor(mm, msk));
        float sum = 0.f;
#pragma unroll
        for (int nt = 0; nt < 4; ++nt) { float e = __expf(sc[nt][r] - mm); sc[nt][r] = e; sum += e; }
#pragma unroll
        for (int msk = 8; msk >= 1; msk >>= 1) sum += __shfl_xor(sum, msk);
        float inv = 1.f / sum;
#pragma unroll
        for (int nt = 0; nt < 4; ++nt) sc[nt][r] *= inv;
    }
    // ---- Qexp from raw f32 q in regs; S = Qexp . Ksum ----
    unsigned qe[4][2];
#pragma unroll
    for (int it = 0; it < 4; ++it) {
        int idx = it * 256 + t;
        int r = idx >> 4, c4 = idx & 15;
        float am_ = alpha * lqmax[r];
        float e0 = __expf(alpha * qraw[it].x - am_);
        float e1 = __expf(alpha * qraw[it].y - am_);
        float e2 = __expf(alpha * qraw[it].z - am_);
        float e3 = __expf(alpha * qraw[it].w - am_);
        float4 ks4 = *(const float4*)&lksum[c4 * 4];
        float dot = e0 * ks4.x + e1 * ks4.y + e2 * ks4.z + e3 * ks4.w;
#pragma unroll
        for (int msk = 8; msk >= 1; msk >>= 1) dot += __shfl_xor(dot, msk);
        if (c4 == 0) lsinv[r] = 1.f / (dot + 1e-8f);
        qe[it][0] = (unsigned)(unsigned short)f2b(e0) | ((unsigned)(unsigned short)f2b(e1) << 16);
        qe[it][1] = (unsigned)(unsigned short)f2b(e2) | ((unsigned)(unsigned short)f2b(e3) << 16);
    }
    __syncthreads();   // all reads of qb/kb complete
    // ---- write probs -> kb (pi-permuted cols to match vtb), Qexp -> qb ----
#pragma unroll
    for (int it = 0; it < 4; ++it) {
        int idx = it * 256 + t;
        int r = idx >> 4, c4 = idx & 15;
        *(unsigned*)&qb[r][c4 * 4] = qe[it][0];
        *(unsigned*)&qb[r][c4 * 4 + 2] = qe[it][1];
    }
#pragma unroll
    for (int nt = 0; nt < 4; ++nt)
#pragma unroll
        for (int r = 0; r < 4; ++r)
            kb[w * 16 + q16 * 4 + r][4 * am + nt] = f2b(sc[nt][r]);   // col = pi(n)
    __syncthreads();

    // ---- diag = P @ V ; lln = Qexp @ KV ----
    short8 pa0 = *(const short8*)&kb[w * 16 + am][ak8];
    short8 pa1 = *(const short8*)&kb[w * 16 + am][32 + ak8];
    short8 qa0 = *(const short8*)&qb[w * 16 + am][ak8];
    short8 qa1 = *(const short8*)&qb[w * 16 + am][32 + ak8];
    f32x4 o[4], acc[4];
#pragma unroll
    for (int i = 0; i < 4; ++i) { o[i] = (f32x4)0.f; acc[i] = (f32x4)0.f; }
#pragma unroll
    for (int nt = 0; nt < 4; ++nt) {
        short4v v0a = *(const short4v*)&vtb[nt * 16 + am][ak8];
        short4v v0b = *(const short4v*)&vtb[nt * 16 + am][ak8 + 4];
        short4v v1a = *(const short4v*)&vtb[nt * 16 + am][32 + ak8];
        short4v v1b = *(const short4v*)&vtb[nt * 16 + am][32 + ak8 + 4];
        short8 vb0 = __builtin_shufflevector(v0a, v0b, 0, 1, 2, 3, 4, 5, 6, 7);
        short8 vb1 = __builtin_shufflevector(v1a, v1b, 0, 1, 2, 3, 4, 5, 6, 7);
        o[nt] = MFMA16(pa0, vb0, o[nt]);
        o[nt] = MFMA16(pa1, vb1, o[nt]);
        short8 kb0 = *(const short8*)&kvb[nt * 16 + am][ak8];
        short8 kb1 = *(const short8*)&kvb[nt * 16 + am][32 + ak8];
        acc[nt] = MFMA16(qa0, kb0, acc[nt]);
        acc[nt] = MFMA16(qa1, kb1, acc[nt]);
    }
    // ---- epilogue: out = 0.5*(lln/S + diag) ----
#pragma unroll
    for (int r = 0; r < 4; ++r) {
        int row = w * 16 + q16 * 4 + r;
        float si = lsinv[row];
#pragma unroll
        for (int nt = 0; nt < 4; ++nt)
            out[base + (long)row * DIM + nt * 16 + am] = 0.5f * (acc[nt][r] * si + o[nt][r]);
    }
}

extern "C" void kernel_launch(void* const* d_in, const int* in_sizes, int n_in,
                              void* d_out, int out_size, void* d_ws, size_t ws_size,
                              hipStream_t stream) {
    const float* q = (const float*)d_in[0];
    const float* k = (const float*)d_in[1];
    const float* v = (const float*)d_in[2];
    float* out = (float*)d_out;
    float* ws = (float*)d_ws;
    float* params = ws + 5120;
    float* KVt    = ws + 8192;
    float* Ksum   = ws + 270336;
    float* kvpart = ws + 274432;
    float* kspart = ws + 2371584;

    reduce_stats<<<2048, 256, 0, stream>>>(q, k, ws);
    compute_params<<<1, 256, 0, stream>>>(ws);
    kv_kernel<<<512, 512, 0, stream>>>(k, v, params, kvpart, kspart);
    kv_reduce<<<1040, 256, 0, stream>>>(kvpart, kspart, KVt, Ksum);
    fused_kernel<<<4096, 256, 0, stream>>>(q, k, v, params, Ksum, KVt, out);
}